// Round 1
// baseline (162.036 us; speedup 1.0000x reference)
//
#include <hip/hip_runtime.h>

#define GX 432
#define GY 496
#define GZ 1
#define G_TOTAL (GX * GY * GZ) /* 214272 */
#define MAX_PTS 32
#define MAX_VOX 20000
#define CAP 64
#define SCAN_CHUNK 4096

// Compute voxel cell of a point with IEEE float32 ops exactly matching the
// reference: c = floor((p - lo)/vs), lo = [0, -39.68, -3], vs = [.16,.16,4].
__device__ __forceinline__ int cell_of(float4 p, bool& ok) {
    float fx = floorf((p.x - 0.0f) / 0.16f);
    float fy = floorf((p.y + 39.68f) / 0.16f);
    float fz = floorf((p.z + 3.0f) / 4.0f);
    int cx = (int)fx, cy = (int)fy, cz = (int)fz;
    ok = (cx >= 0 && cx < GX && cy >= 0 && cy < GY && cz >= 0 && cz < GZ);
    return (cz * GY + cy) * GX + cx;
}

// Pass A: first[cell] = min point index touching that cell.
__global__ void passA(const float4* __restrict__ pts, int* __restrict__ first, int n) {
    int i = blockIdx.x * blockDim.x + threadIdx.x;
    if (i >= n) return;
    bool ok;
    int lin = cell_of(pts[i], ok);
    if (ok) atomicMin(&first[lin], i);
}

// Scan phase 1: flag[i] = (point i is the first point of its cell).
// Block handles SCAN_CHUNK points; writes per-point block-local exclusive
// scan (u16) and the block total.
__global__ void passScan1(const float4* __restrict__ pts, const int* __restrict__ first,
                          unsigned short* __restrict__ localExcl, int* __restrict__ blockSums,
                          int n) {
    __shared__ unsigned short fsh[SCAN_CHUNK];
    __shared__ int wsum[4];
    __shared__ int wexc[4];
    int b = blockIdx.x, t = threadIdx.x;
    int base = b * SCAN_CHUNK;
    for (int k = 0; k < 16; k++) {
        int i = base + t + k * 256;
        int fl = 0;
        if (i < n) {
            bool ok;
            int lin = cell_of(pts[i], ok);
            if (ok) fl = (first[lin] == i) ? 1 : 0;
        }
        fsh[t + k * 256] = (unsigned short)fl;
    }
    __syncthreads();
    // thread-local sequential exclusive scan over its contiguous 16
    int offm = t * 16;
    unsigned short loc[16];
    int s = 0;
    for (int k = 0; k < 16; k++) {
        loc[k] = (unsigned short)s;
        s += fsh[offm + k];
    }
    // wave64 inclusive scan of per-thread totals
    int lane = t & 63, w = t >> 6;
    int x = s;
    for (int d = 1; d < 64; d <<= 1) {
        int y = __shfl_up(x, d, 64);
        if (lane >= d) x += y;
    }
    if (lane == 63) wsum[w] = x;
    __syncthreads();
    if (t == 0) {
        int a = 0;
        for (int j = 0; j < 4; j++) { wexc[j] = a; a += wsum[j]; }
        blockSums[b] = a;
    }
    __syncthreads();
    int texcl = wexc[w] + x - s;  // block-local exclusive offset of this thread
    // all reads of fsh are behind the barriers above; safe to overwrite
    for (int k = 0; k < 16; k++) fsh[offm + k] = (unsigned short)(texcl + loc[k]);
    __syncthreads();
    for (int k = 0; k < 16; k++) {
        int i = base + t + k * 256;
        if (i < n) localExcl[i] = fsh[t + k * 256];
    }
}

// Scan phase 2: exclusive scan of block sums (numBlocks <= 1024), single block.
// Also writes num_voxels = min(total_nonempty_cells, MAX_VOX) as float.
__global__ void passScan2(int* __restrict__ blockSums, int numBlocks,
                          float* __restrict__ numVoxOut) {
    __shared__ int wsum[16];
    __shared__ int wexc[16];
    int t = threadIdx.x;
    int v = (t < numBlocks) ? blockSums[t] : 0;
    int lane = t & 63, w = t >> 6;
    int x = v;
    for (int d = 1; d < 64; d <<= 1) {
        int y = __shfl_up(x, d, 64);
        if (lane >= d) x += y;
    }
    if (lane == 63) wsum[w] = x;
    __syncthreads();
    if (t == 0) {
        int a = 0;
        for (int j = 0; j < 16; j++) { wexc[j] = a; a += wsum[j]; }
        int nv = a < MAX_VOX ? a : MAX_VOX;
        numVoxOut[0] = (float)nv;
    }
    __syncthreads();
    int excl = wexc[w] + x - v;
    if (t < numBlocks) blockSums[t] = excl;
}

// Pass E: per point, compute voxel rank; if < MAX_VOX append index to the
// voxel's list and (for the first point) record the cell id of that rank.
__global__ void passE(const float4* __restrict__ pts, const int* __restrict__ first,
                      const unsigned short* __restrict__ localExcl,
                      const int* __restrict__ blockOffs, int* __restrict__ vcount,
                      int* __restrict__ cellOfRank, int* __restrict__ list, int n) {
    int i = blockIdx.x * blockDim.x + threadIdx.x;
    if (i >= n) return;
    bool ok;
    int lin = cell_of(pts[i], ok);
    if (!ok) return;
    int f = first[lin];
    int vr = blockOffs[f >> 12] + (int)localExcl[f];
    if (vr >= MAX_VOX) return;
    int pos = atomicAdd(&vcount[vr], 1);
    if (pos < CAP) list[vr * CAP + pos] = i;
    if (f == i) cellOfRank[vr] = lin;
}

// Pass F: one 64-thread block per voxel. Sort the collected point indices
// ascending (rank-by-count, LDS broadcast), write first <=32 points, plus
// num_points and coors rows.
__global__ void passF(const float4* __restrict__ pts, const int* __restrict__ vcount,
                      const int* __restrict__ cellOfRank, const int* __restrict__ list,
                      float4* __restrict__ voxOut, float* __restrict__ coorsOut,
                      float* __restrict__ npOut) {
    __shared__ int s[CAP];
    int v = blockIdx.x;
    int t = threadIdx.x;  // 0..63
    int cnt = vcount[v];
    int m = cnt < CAP ? cnt : CAP;
    s[t] = (t < m) ? list[v * CAP + t] : 0x7FFFFFFF;
    __syncthreads();
    int my = s[t];
    int r = 0;
#pragma unroll
    for (int j = 0; j < CAP; j++) r += (s[j] < my) ? 1 : 0;  // same-address LDS: broadcast
    if (t < m && r < MAX_PTS) {
        float4 p = pts[my];
        voxOut[v * MAX_PTS + r] = p;
    }
    if (t == 0) {
        npOut[v] = (float)(cnt < MAX_PTS ? cnt : MAX_PTS);
        int cell = cellOfRank[v];
        if (cell < 0) {
            coorsOut[3 * v + 0] = -1.0f;
            coorsOut[3 * v + 1] = -1.0f;
            coorsOut[3 * v + 2] = -1.0f;
        } else {
            int cz = cell / (GX * GY);
            int rem = cell % (GX * GY);
            int cy = rem / GX;
            int cx = rem % GX;
            coorsOut[3 * v + 0] = (float)cz;
            coorsOut[3 * v + 1] = (float)cy;
            coorsOut[3 * v + 2] = (float)cx;
        }
    }
}

extern "C" void kernel_launch(void* const* d_in, const int* in_sizes, int n_in,
                              void* d_out, int out_size, void* d_ws, size_t ws_size,
                              hipStream_t stream) {
    const float4* pts = (const float4*)d_in[0];
    int n = in_sizes[0] / 4;  // 2,000,000 points x 4 features

    // Workspace layout (256B-aligned regions)
    char* ws = (char*)d_ws;
    size_t off = 0;
    auto alloc = [&](size_t bytes) -> void* {
        void* p = (void*)(ws + off);
        off = (off + bytes + 255) & ~(size_t)255;
        return p;
    };
    int* first = (int*)alloc((size_t)G_TOTAL * 4);
    unsigned short* localExcl = (unsigned short*)alloc((size_t)n * 2);
    int* blockSums = (int*)alloc(1024 * 4);
    int* vcount = (int*)alloc((size_t)MAX_VOX * 4);
    int* cellOfRank = (int*)alloc((size_t)MAX_VOX * 4);
    int* list = (int*)alloc((size_t)MAX_VOX * CAP * 4);
    (void)ws_size;

    float* out = (float*)d_out;
    float4* voxOut = (float4*)out;                       // 20000*32*4 floats
    float* coorsOut = out + (size_t)MAX_VOX * MAX_PTS * 4;  // 20000*3
    float* npOut = coorsOut + (size_t)MAX_VOX * 3;          // 20000
    float* nvOut = npOut + MAX_VOX;                         // 1

    // Inits (ws and d_out are poisoned 0xAA before every replay)
    hipMemsetAsync(first, 0x7F, (size_t)G_TOTAL * 4, stream);      // > any point idx
    hipMemsetAsync(vcount, 0, (size_t)MAX_VOX * 4, stream);
    hipMemsetAsync(cellOfRank, 0xFF, (size_t)MAX_VOX * 4, stream); // -1
    hipMemsetAsync(d_out, 0, (size_t)out_size * 4, stream);

    int nb = (n + 255) / 256;
    int numBlocks = (n + SCAN_CHUNK - 1) / SCAN_CHUNK;  // 489 for n=2e6

    passA<<<nb, 256, 0, stream>>>(pts, first, n);
    passScan1<<<numBlocks, 256, 0, stream>>>(pts, first, localExcl, blockSums, n);
    passScan2<<<1, 1024, 0, stream>>>(blockSums, numBlocks, nvOut);
    passE<<<nb, 256, 0, stream>>>(pts, first, localExcl, blockSums, vcount, cellOfRank, list, n);
    passF<<<MAX_VOX, 64, 0, stream>>>(pts, vcount, cellOfRank, list, voxOut, coorsOut, npOut);
}

// Round 2
// 160.874 us; speedup vs baseline: 1.0072x; 1.0072x over previous
//
#include <hip/hip_runtime.h>

#define GX 432
#define GY 496
#define G_TOTAL (GX * GY) /* 214272, GZ=1 */
#define MAX_PTS 32
#define MAX_VOX 20000
#define CAP 64
#define NXCD 8

typedef unsigned long long u64;

__device__ __forceinline__ int xcc_id() {
    int x;
    asm volatile("s_getreg_b32 %0, hwreg(HW_REG_XCC_ID)" : "=s"(x));
    return x & 7;
}

// IEEE float32 ops exactly matching the reference:
// c = floor((p - lo)/vs), lo = [0, -39.68, -3], vs = [.16,.16,4].
__device__ __forceinline__ int cell_of(float4 p, bool& ok) {
    float fx = floorf((p.x - 0.0f) / 0.16f);
    float fy = floorf((p.y + 39.68f) / 0.16f);
    float fz = floorf((p.z + 3.0f) / 4.0f);
    int cx = (int)fx, cy = (int)fy, cz = (int)fz;
    ok = (cx >= 0 && cx < GX && cy >= 0 && cy < GY && cz == 0);
    return cy * GX + cx;
}

// Pass 1: per point, store cell id (or -1) and XCD-local atomicMin of index.
__global__ __launch_bounds__(256) void pass1(const float4* __restrict__ pts,
                                             int* __restrict__ lin,
                                             int* __restrict__ first8, int n) {
    int i = blockIdx.x * 256 + threadIdx.x;
    if (i >= n) return;
    float4 p = pts[i];
    bool ok;
    int c = cell_of(p, ok);
    lin[i] = ok ? c : -1;
    if (ok) {
        int* dst = first8 + (size_t)xcc_id() * G_TOTAL + c;
        // workgroup scope: RMW performed in the local (per-XCD) L2.
        // Safe: all writers to copy k are blocks resident on XCD k.
        __hip_atomic_fetch_min(dst, i, __ATOMIC_RELAXED, __HIP_MEMORY_SCOPE_WORKGROUP);
    }
}

// Merge the 8 per-XCD first copies; mark first-point bitmap (per-XCD copies).
__global__ __launch_bounds__(256) void mergeMark(const int* __restrict__ first8,
                                                 int* __restrict__ first,
                                                 u64* __restrict__ bitmap8,
                                                 int W, int n) {
    int c = blockIdx.x * 256 + threadIdx.x;
    if (c >= G_TOTAL) return;
    int f = first8[c];
#pragma unroll
    for (int k = 1; k < NXCD; k++) f = min(f, first8[(size_t)k * G_TOTAL + c]);
    first[c] = f;
    if (f < n) {
        u64* dst = bitmap8 + (size_t)xcc_id() * W + (f >> 6);
        __hip_atomic_fetch_or(dst, 1ull << (f & 63), __ATOMIC_RELAXED,
                              __HIP_MEMORY_SCOPE_WORKGROUP);
    }
}

// Scan A: merge 8 bitmaps -> bits[], per-block popcount sums.
__global__ __launch_bounds__(256) void kScanA(const u64* __restrict__ bitmap8,
                                              u64* __restrict__ bits,
                                              int* __restrict__ sums, int W) {
    __shared__ int wsum[4];
    int t = threadIdx.x;
    int wi = blockIdx.x * 256 + t;
    u64 m = 0;
    if (wi < W) {
#pragma unroll
        for (int k = 0; k < NXCD; k++) m |= bitmap8[(size_t)k * W + wi];
        bits[wi] = m;
    }
    int v = __popcll(m);
    for (int d = 32; d >= 1; d >>= 1) v += __shfl_down(v, d, 64);
    if ((t & 63) == 0) wsum[t >> 6] = v;
    __syncthreads();
    if (t == 0) sums[blockIdx.x] = wsum[0] + wsum[1] + wsum[2] + wsum[3];
}

// Scan B: exclusive scan of block sums (nb <= 128); writes num_voxels.
__global__ __launch_bounds__(128) void kScanB(int* __restrict__ sums, int nb,
                                              float* __restrict__ nvOut) {
    __shared__ int wsum[2], wexc[2];
    int t = threadIdx.x;
    int v = (t < nb) ? sums[t] : 0;
    int lane = t & 63, w = t >> 6;
    int x = v;
    for (int d = 1; d < 64; d <<= 1) {
        int y = __shfl_up(x, d, 64);
        if (lane >= d) x += y;
    }
    if (lane == 63) wsum[w] = x;
    __syncthreads();
    if (t == 0) {
        int a = 0;
        for (int j = 0; j < 2; j++) { wexc[j] = a; a += wsum[j]; }
        nvOut[0] = (float)(a < MAX_VOX ? a : MAX_VOX);
    }
    __syncthreads();
    if (t < nb) sums[t] = wexc[w] + x - v;
}

// Scan C: per-word exclusive popcount prefix.
__global__ __launch_bounds__(256) void kScanC(const u64* __restrict__ bits,
                                              const int* __restrict__ sumsExcl,
                                              unsigned* __restrict__ wordExcl, int W) {
    __shared__ int wsum[4], wexc[4];
    int t = threadIdx.x;
    int wi = blockIdx.x * 256 + t;
    u64 m = (wi < W) ? bits[wi] : 0;
    int v = __popcll(m);
    int lane = t & 63, w = t >> 6;
    int x = v;
    for (int d = 1; d < 64; d <<= 1) {
        int y = __shfl_up(x, d, 64);
        if (lane >= d) x += y;
    }
    if (lane == 63) wsum[w] = x;
    __syncthreads();
    if (t == 0) {
        int a = 0;
        for (int j = 0; j < 4; j++) { wexc[j] = a; a += wsum[j]; }
    }
    __syncthreads();
    if (wi < W) wordExcl[wi] = sumsExcl[blockIdx.x] + wexc[w] + x - v;
}

// Rank cells by first-appearance; record cell id per kept rank.
__global__ __launch_bounds__(256) void rankCells(const int* __restrict__ first,
                                                 const u64* __restrict__ bits,
                                                 const unsigned* __restrict__ wordExcl,
                                                 int* __restrict__ rank,
                                                 int* __restrict__ cellOfRank, int n) {
    int c = blockIdx.x * 256 + threadIdx.x;
    if (c >= G_TOTAL) return;
    int f = first[c];
    if (f >= n) return;
    int w = f >> 6;
    int vr = (int)wordExcl[w] + __popcll(bits[w] & ((1ull << (f & 63)) - 1ull));
    rank[c] = vr;
    if (vr < MAX_VOX) cellOfRank[vr] = c;
}

// Pass 5: append point indices into kept voxels' lists.
// vcount starts at -1 (0xFF memset); atomicAdd returns old, pos = old+1.
__global__ __launch_bounds__(256) void pass5(const int* __restrict__ lin,
                                             const int* __restrict__ rank,
                                             int* __restrict__ vcount,
                                             int* __restrict__ list, int n) {
    int i = blockIdx.x * 256 + threadIdx.x;
    if (i >= n) return;
    int c = lin[i];
    if (c < 0) return;
    int vr = rank[c];
    if (vr >= MAX_VOX) return;
    int pos = atomicAdd(&vcount[vr], 1) + 1;
    if (pos < CAP) list[vr * CAP + pos] = i;
}

// Pass F: one 64-thread block per voxel; sort indices by counting (LDS
// broadcast), write all 32 slots (zeros for empty) + num_points + coors.
__global__ __launch_bounds__(64) void passF(const float4* __restrict__ pts,
                                            const int* __restrict__ vcount,
                                            const int* __restrict__ cellOfRank,
                                            const int* __restrict__ list,
                                            float4* __restrict__ voxOut,
                                            float* __restrict__ coorsOut,
                                            float* __restrict__ npOut) {
    __shared__ int s[CAP];
    __shared__ int slotPt[MAX_PTS];
    int v = blockIdx.x;
    int t = threadIdx.x;
    int cnt = vcount[v] + 1;
    int m = cnt < CAP ? cnt : CAP;
    s[t] = (t < m) ? list[v * CAP + t] : 0x7FFFFFFF;
    if (t < MAX_PTS) slotPt[t] = -1;
    __syncthreads();
    int my = s[t];
    int r = 0;
#pragma unroll
    for (int j = 0; j < CAP; j++) r += (s[j] < my) ? 1 : 0;  // broadcast reads
    if (t < m && r < MAX_PTS) slotPt[r] = my;
    __syncthreads();
    if (t < MAX_PTS) {
        int p = slotPt[t];
        float4 val = make_float4(0.f, 0.f, 0.f, 0.f);
        if (p >= 0) val = pts[p];
        voxOut[(size_t)v * MAX_PTS + t] = val;
    }
    if (t == 0) {
        npOut[v] = (float)(cnt < MAX_PTS ? cnt : MAX_PTS);
        int cell = cellOfRank[v];
        if (cell < 0) {
            coorsOut[3 * v + 0] = -1.0f;
            coorsOut[3 * v + 1] = -1.0f;
            coorsOut[3 * v + 2] = -1.0f;
        } else {
            int cy = cell / GX;
            int cx = cell % GX;
            coorsOut[3 * v + 0] = 0.0f;  // cz (GZ==1)
            coorsOut[3 * v + 1] = (float)cy;
            coorsOut[3 * v + 2] = (float)cx;
        }
    }
}

extern "C" void kernel_launch(void* const* d_in, const int* in_sizes, int n_in,
                              void* d_out, int out_size, void* d_ws, size_t ws_size,
                              hipStream_t stream) {
    const float4* pts = (const float4*)d_in[0];
    int n = in_sizes[0] / 4;  // 2,000,000
    int W = (n + 63) >> 6;    // 31250 bitmap words

    char* ws = (char*)d_ws;
    size_t off = 0;
    auto alloc = [&](size_t bytes) -> void* {
        void* p = (void*)(ws + off);
        off = (off + bytes + 255) & ~(size_t)255;
        return p;
    };
    int* first8 = (int*)alloc((size_t)NXCD * G_TOTAL * 4);
    int* first = (int*)alloc((size_t)G_TOTAL * 4);
    int* lin = (int*)alloc((size_t)n * 4);
    u64* bitmap8 = (u64*)alloc((size_t)NXCD * W * 8);
    u64* bits = (u64*)alloc((size_t)W * 8);
    unsigned* wordExcl = (unsigned*)alloc((size_t)W * 4);
    int* sums = (int*)alloc(128 * 4);
    int* rank = (int*)alloc((size_t)G_TOTAL * 4);
    size_t vcount_off = off;
    int* vcount = (int*)alloc((size_t)MAX_VOX * 4);
    int* cellOfRank = (int*)alloc((size_t)MAX_VOX * 4);
    size_t vc_span = off - vcount_off;  // covers vcount + pad + cellOfRank
    int* list = (int*)alloc((size_t)MAX_VOX * CAP * 4);
    (void)ws_size;

    float* out = (float*)d_out;
    float4* voxOut = (float4*)out;                          // 20000*32*4
    float* coorsOut = out + (size_t)MAX_VOX * MAX_PTS * 4;  // 20000*3
    float* npOut = coorsOut + (size_t)MAX_VOX * 3;          // 20000
    float* nvOut = npOut + MAX_VOX;                         // 1

    hipMemsetAsync(first8, 0x7F, (size_t)NXCD * G_TOTAL * 4, stream);  // INF
    hipMemsetAsync(bitmap8, 0x00, (size_t)NXCD * W * 8, stream);
    hipMemsetAsync(vcount, 0xFF, vc_span, stream);  // vcount=-1, cellOfRank=-1

    int nbP = (n + 255) / 256;            // 7813
    int nbC = (G_TOTAL + 255) / 256;      // 837
    int nbW = (W + 255) / 256;            // 123

    pass1<<<nbP, 256, 0, stream>>>(pts, lin, first8, n);
    mergeMark<<<nbC, 256, 0, stream>>>(first8, first, bitmap8, W, n);
    kScanA<<<nbW, 256, 0, stream>>>(bitmap8, bits, sums, W);
    kScanB<<<1, 128, 0, stream>>>(sums, nbW, nvOut);
    kScanC<<<nbW, 256, 0, stream>>>(bits, sums, wordExcl, W);
    rankCells<<<nbC, 256, 0, stream>>>(first, bits, wordExcl, rank, cellOfRank, n);
    pass5<<<nbP, 256, 0, stream>>>(lin, rank, vcount, list, n);
    passF<<<MAX_VOX, 64, 0, stream>>>(pts, vcount, cellOfRank, list, voxOut, coorsOut, npOut);
}